// Round 10
// baseline (697.253 us; speedup 1.0000x reference)
//
#include <hip/hip_runtime.h>

// VectorQuantizer on MI355X — round 10: candidate-split blocks (4/CU),
// ballot hot-masks, u64-atomicMin merge, coalesced epilogue.
// x: [32768, 64] f32, codebook: [8192, 64] f32.
// out (f32): [0..2097152) quantized, [2097152] loss, [2097153..) indices as floats.
//
// Block = 512 thr (8 waves) x 64 rows x 4096 cands (half the codebook);
// grid = 512 rowgroups x 2 halves = 1024 blocks -> 4 blocks/CU.
// Pass 1: per-(row, tile-pair) max of t_k = x.e_k - ||e_k||^2/2 into LDS
//   (stmax[8][8][64] f32, 16 KB). Local threshold = local max - 1.5e-4.
// Hot masks per (pair, rt-half) via __ballot (registers; no LDS scan).
// Pass 2: re-MFMA only hot pairs/rt, gather exact candidates into LDS.
// Finalize: wave-per-8-rows EXACT rescore (round-2-validated numpy numerics),
//   lexicographic wave-reduce, then atomicMin(u64 packed sortable-score|idx)
//   -> global first-min merge across the two halves, bit-exact.
// Epilogue: read winner, coalesced gather + out_idx + loss partials.

#define NUM_E   8192
#define DIM     64
#define KPAD    80
#define NROWS   32768
#define NELEM   2097152
#define CAP     32
#define TMARGIN 1.5e-4f
#define ROWS_PB 64
#define WAVES   8
#define NT      16          // tiles of 32 cands per wave (512 cands/wave)
#define FLTMAX  3.402823466e+38f

using bf16x8 = __attribute__((ext_vector_type(8))) short;
using f32x16 = __attribute__((ext_vector_type(16))) float;
typedef unsigned long long u64;

__device__ __forceinline__ unsigned int f2bf(float f) {
    unsigned int u = __float_as_uint(f);
    return (u + 0x7FFFu + ((u >> 16) & 1u)) >> 16;   // RNE to bf16
}

// numpy pairwise_sum(n=64) of elementwise squares (validated bit-exact r2+).
__device__ __forceinline__ float np_sumsq64_f4(const float4 v[16]) {
    float r0 = __fmul_rn(v[0].x, v[0].x), r1 = __fmul_rn(v[0].y, v[0].y);
    float r2 = __fmul_rn(v[0].z, v[0].z), r3 = __fmul_rn(v[0].w, v[0].w);
    float r4 = __fmul_rn(v[1].x, v[1].x), r5 = __fmul_rn(v[1].y, v[1].y);
    float r6 = __fmul_rn(v[1].z, v[1].z), r7 = __fmul_rn(v[1].w, v[1].w);
#pragma unroll
    for (int t = 1; t < 8; ++t) {
        r0 = __fadd_rn(r0, __fmul_rn(v[2 * t].x, v[2 * t].x));
        r1 = __fadd_rn(r1, __fmul_rn(v[2 * t].y, v[2 * t].y));
        r2 = __fadd_rn(r2, __fmul_rn(v[2 * t].z, v[2 * t].z));
        r3 = __fadd_rn(r3, __fmul_rn(v[2 * t].w, v[2 * t].w));
        r4 = __fadd_rn(r4, __fmul_rn(v[2 * t + 1].x, v[2 * t + 1].x));
        r5 = __fadd_rn(r5, __fmul_rn(v[2 * t + 1].y, v[2 * t + 1].y));
        r6 = __fadd_rn(r6, __fmul_rn(v[2 * t + 1].z, v[2 * t + 1].z));
        r7 = __fadd_rn(r7, __fmul_rn(v[2 * t + 1].w, v[2 * t + 1].w));
    }
    return __fadd_rn(__fadd_rn(__fadd_rn(r0, r1), __fadd_rn(r2, r3)),
                     __fadd_rn(__fadd_rn(r4, r5), __fadd_rn(r6, r7)));
}

__global__ __launch_bounds__(256)
void vq_prep_cb(const float* __restrict__ cb, float* __restrict__ norms,
                unsigned short* __restrict__ ebuf) {
    const int row = blockIdx.x * 256 + threadIdx.x;
    float4 e[16];
    const float4* p = reinterpret_cast<const float4*>(cb + row * DIM);
#pragma unroll
    for (int c = 0; c < 16; ++c) e[c] = p[c];
    const float nrm = np_sumsq64_f4(e);
    norms[row] = nrm;
    uint2* dst = reinterpret_cast<uint2*>(ebuf + (size_t)row * KPAD);
#pragma unroll
    for (int c = 0; c < 16; ++c) {
        uint2 w;
        w.x = f2bf(e[c].x) | (f2bf(e[c].y) << 16);
        w.y = f2bf(e[c].z) | (f2bf(e[c].w) << 16);
        dst[c] = w;
    }
    unsigned int* tail = reinterpret_cast<unsigned int*>(ebuf + (size_t)row * KPAD + DIM);
    tail[0] = f2bf(-0.5f * nrm);
#pragma unroll
    for (int j = 1; j < 8; ++j) tail[j] = 0u;
}

// 5 dependent MFMAs + depth-4 max tree -> OUT = tile max (per lane).
#define TILE_MAXV(AF, RT, OUT) do {                                             \
    f32x16 acc_;                                                                \
    _Pragma("unroll") for (int i_ = 0; i_ < 16; ++i_) acc_[i_] = 0.f;           \
    _Pragma("unroll") for (int k_ = 0; k_ < 5; ++k_)                            \
        acc_ = __builtin_amdgcn_mfma_f32_32x32x16_bf16(AF[k_], bfrag[RT][k_],   \
                                                       acc_, 0, 0, 0);          \
    float m0_ = fmaxf(fmaxf(acc_[0], acc_[1]),  fmaxf(acc_[2], acc_[3]));       \
    float m1_ = fmaxf(fmaxf(acc_[4], acc_[5]),  fmaxf(acc_[6], acc_[7]));       \
    float m2_ = fmaxf(fmaxf(acc_[8], acc_[9]),  fmaxf(acc_[10], acc_[11]));     \
    float m3_ = fmaxf(fmaxf(acc_[12], acc_[13]), fmaxf(acc_[14], acc_[15]));    \
    OUT = fmaxf(fmaxf(m0_, m1_), fmaxf(m2_, m3_));                              \
} while (0)

// Recompute (bit-identical) + gather cands above per-row threshold into LDS.
#define TILE_GATHER(AF, RT, THR, TIDX) do {                                     \
    f32x16 acc_;                                                                \
    _Pragma("unroll") for (int i_ = 0; i_ < 16; ++i_) acc_[i_] = 0.f;           \
    _Pragma("unroll") for (int k_ = 0; k_ < 5; ++k_)                            \
        acc_ = __builtin_amdgcn_mfma_f32_32x32x16_bf16(AF[k_], bfrag[RT][k_],   \
                                                       acc_, 0, 0, 0);          \
    float m0_ = fmaxf(fmaxf(acc_[0], acc_[1]),  fmaxf(acc_[2], acc_[3]));       \
    float m1_ = fmaxf(fmaxf(acc_[4], acc_[5]),  fmaxf(acc_[6], acc_[7]));       \
    float m2_ = fmaxf(fmaxf(acc_[8], acc_[9]),  fmaxf(acc_[10], acc_[11]));     \
    float m3_ = fmaxf(fmaxf(acc_[12], acc_[13]), fmaxf(acc_[14], acc_[15]));    \
    float tm_ = fmaxf(fmaxf(m0_, m1_), fmaxf(m2_, m3_));                        \
    if (__any(tm_ >= (THR))) {                                                  \
        const int lr_ = (RT) * 32 + l31;                                        \
        _Pragma("unroll") for (int r_ = 0; r_ < 16; ++r_) {                     \
            if (acc_[r_] >= (THR)) {                                            \
                const int crow_ = (r_ & 3) + 8 * (r_ >> 2) + 4 * half;          \
                const int pos_ = atomicAdd(&scnt[lr_], 1);                      \
                if (pos_ < CAP)                                                 \
                    sslots[lr_][pos_] = candbase + (TIDX) * 32 + crow_;         \
            }                                                                   \
        }                                                                       \
    }                                                                           \
} while (0)

__global__ __launch_bounds__(512, 8)
void vq_fused_kernel(const unsigned short* __restrict__ ebuf,
                     const float* __restrict__ x, const float* __restrict__ cb,
                     const float* __restrict__ norms,
                     u64* __restrict__ rowbest) {
    const int tid  = threadIdx.x;
    const int lane = tid & 63;
    const int wid  = tid >> 6;          // 0..7: candidate sub-split
    const int half = lane >> 5;
    const int l31  = lane & 31;
    const int rowbase  = (blockIdx.x >> 1) * ROWS_PB;
    const int candbase = (blockIdx.x & 1) * 4096 + wid * 512;

    __shared__ float stmax[WAVES][NT / 2][ROWS_PB];   // 16 KB
    __shared__ float sm[WAVES][ROWS_PB];              // 2 KB
    __shared__ float sthr[ROWS_PB];
    __shared__ int   scnt[ROWS_PB];
    __shared__ int   sslots[ROWS_PB][CAP];            // 8 KB

    if (tid < ROWS_PB) scnt[tid] = 0;

    // ---- B fragments built in-kernel from x (bit-identical f2bf packing) ----
    bf16x8 bfrag[2][5];
#pragma unroll
    for (int rt = 0; rt < 2; ++rt) {
        const float* xrow = x + (size_t)(rowbase + rt * 32 + l31) * DIM;
#pragma unroll
        for (int ks = 0; ks < 4; ++ks) {
            const float4* p = reinterpret_cast<const float4*>(xrow + ks * 16 + half * 8);
            float4 v0 = p[0], v1 = p[1];
            bf16x8 f;
            f[0] = (short)f2bf(v0.x); f[1] = (short)f2bf(v0.y);
            f[2] = (short)f2bf(v0.z); f[3] = (short)f2bf(v0.w);
            f[4] = (short)f2bf(v1.x); f[5] = (short)f2bf(v1.y);
            f[6] = (short)f2bf(v1.z); f[7] = (short)f2bf(v1.w);
            bfrag[rt][ks] = f;
        }
        bf16x8 ft;   // K = [64,80): padded x tail = [1.0, 0 x15]
#pragma unroll
        for (int j = 0; j < 8; ++j) ft[j] = 0;
        if (half == 0) ft[0] = (short)0x3F80;   // bf16(1.0)
        bfrag[rt][4] = ft;
    }

    const unsigned short* abase = ebuf + (size_t)(candbase + l31) * KPAD + half * 8;

    // ---- pass 1: per-(row, tile-pair) max into LDS, 2-deep A prefetch ----
    bf16x8 a0[5], a1[5];
#pragma unroll
    for (int ks = 0; ks < 5; ++ks)
        a0[ks] = *reinterpret_cast<const bf16x8*>(abase + ks * 16);

    for (int t = 0; t < NT; t += 2) {
        const unsigned short* ap1 = abase + (size_t)(t + 1) * 32 * KPAD;
#pragma unroll
        for (int ks = 0; ks < 5; ++ks)
            a1[ks] = *reinterpret_cast<const bf16x8*>(ap1 + ks * 16);
        float m00, m01;
        TILE_MAXV(a0, 0, m00);
        TILE_MAXV(a0, 1, m01);
        const unsigned short* ap2 = abase + (size_t)((t + 2) & (NT - 1)) * 32 * KPAD;
#pragma unroll
        for (int ks = 0; ks < 5; ++ks)
            a0[ks] = *reinterpret_cast<const bf16x8*>(ap2 + ks * 16);
        float m10, m11;
        TILE_MAXV(a1, 0, m10);
        TILE_MAXV(a1, 1, m11);
        float p0 = fmaxf(m00, m10);
        float p1 = fmaxf(m01, m11);
        p0 = fmaxf(p0, __shfl_xor(p0, 32));      // merge cand-halves per row
        p1 = fmaxf(p1, __shfl_xor(p1, 32));
        if (half == 0) stmax[wid][t >> 1][l31]      = p0;
        else           stmax[wid][t >> 1][32 + l31] = p1;
    }
    __syncthreads();

    // ---- block max fold -> per-row local threshold ----
    {
        const int w = tid >> 6, r = tid & 63;
        float m = stmax[w][0][r];
#pragma unroll
        for (int tp = 1; tp < NT / 2; ++tp) m = fmaxf(m, stmax[w][tp][r]);
        sm[w][r] = m;
    }
    __syncthreads();
    if (tid < ROWS_PB) {
        float m = sm[0][tid];
#pragma unroll
        for (int w = 1; w < WAVES; ++w) m = fmaxf(m, sm[w][tid]);
        sthr[tid] = m - TMARGIN;
    }
    __syncthreads();

    // ---- hot masks per (pair, rt-half) via ballot (lane = row) ----
    unsigned int hot0 = 0, hot1 = 0;
    {
        const float th = sthr[lane];
#pragma unroll
        for (int tp = 0; tp < NT / 2; ++tp) {
            const u64 b = __ballot(stmax[wid][tp][lane] >= th);
            if (b & 0xFFFFFFFFull) hot0 |= 1u << tp;
            if (b >> 32)           hot1 |= 1u << tp;
        }
    }

    // ---- pass 2: re-MFMA only hot pairs (per rt), per-candidate gather ----
    {
        const float thr0 = sthr[l31];
        const float thr1 = sthr[32 + l31];
        unsigned int mu = hot0 | hot1;
        while (mu) {
            const int tp = __ffs(mu) - 1;
            const unsigned int bit = 1u << tp;
            mu &= mu - 1;
            const int t0 = 2 * tp;
            const unsigned short* ap0 = abase + (size_t)t0 * 32 * KPAD;
            const unsigned short* ap1 = abase + (size_t)(t0 + 1) * 32 * KPAD;
#pragma unroll
            for (int ks = 0; ks < 5; ++ks) {
                a0[ks] = *reinterpret_cast<const bf16x8*>(ap0 + ks * 16);
                a1[ks] = *reinterpret_cast<const bf16x8*>(ap1 + ks * 16);
            }
            if (hot0 & bit) {
                TILE_GATHER(a0, 0, thr0, t0);
                TILE_GATHER(a1, 0, thr0, t0 + 1);
            }
            if (hot1 & bit) {
                TILE_GATHER(a0, 1, thr1, t0);
                TILE_GATHER(a1, 1, thr1, t0 + 1);
            }
        }
    }
    __syncthreads();

    // ---- finalize: wave per 8 rows; exact rescore + u64 atomicMin merge ----
    for (int i = 0; i < 8; ++i) {
        const int lr = wid * 8 + i;
        const int r  = rowbase + lr;
        const int c0 = scnt[lr];
        const bool okc = (c0 <= CAP);
        const int ncand = okc ? c0 : 4096;   // overflow -> scan this block's half
        float4 xr[16];
        const float4* xp = reinterpret_cast<const float4*>(x + (size_t)r * DIM);
#pragma unroll
        for (int c = 0; c < 16; ++c) xr[c] = xp[c];
        const float sx = np_sumsq64_f4(xr);   // identical fn -> bit-identical
        float best = FLTMAX;
        int bi = 0x7FFFFFFF;
        for (int j = lane; j < ncand; j += 64) {
            const int k = okc ? sslots[lr][j] : ((blockIdx.x & 1) * 4096 + j);
            const float4* ep4 = reinterpret_cast<const float4*>(cb + (size_t)k * DIM);
            float dot = 0.f;   // sequential fmaf chain d=0..63 (exact replication)
#pragma unroll
            for (int c = 0; c < 16; c += 4) {
                float4 e0 = ep4[c], e1 = ep4[c + 1], e2 = ep4[c + 2], e3 = ep4[c + 3];
                dot = fmaf(xr[c].x,     e0.x, dot); dot = fmaf(xr[c].y,     e0.y, dot);
                dot = fmaf(xr[c].z,     e0.z, dot); dot = fmaf(xr[c].w,     e0.w, dot);
                dot = fmaf(xr[c + 1].x, e1.x, dot); dot = fmaf(xr[c + 1].y, e1.y, dot);
                dot = fmaf(xr[c + 1].z, e1.z, dot); dot = fmaf(xr[c + 1].w, e1.w, dot);
                dot = fmaf(xr[c + 2].x, e2.x, dot); dot = fmaf(xr[c + 2].y, e2.y, dot);
                dot = fmaf(xr[c + 2].z, e2.z, dot); dot = fmaf(xr[c + 2].w, e2.w, dot);
                dot = fmaf(xr[c + 3].x, e3.x, dot); dot = fmaf(xr[c + 3].y, e3.y, dot);
                dot = fmaf(xr[c + 3].z, e3.z, dot); dot = fmaf(xr[c + 3].w, e3.w, dot);
            }
            const float t1 = __fadd_rn(sx, norms[k]);
            const float d2 = __fadd_rn(dot, dot);
            const float sc = __fsub_rn(t1, d2);
            if (sc < best || (sc == best && k < bi)) { best = sc; bi = k; }
        }
#pragma unroll
        for (int off = 1; off < 64; off <<= 1) {   // lexicographic first-min
            const float s2 = __shfl_xor(best, off);
            const int   i2 = __shfl_xor(bi, off);
            if (s2 < best || (s2 == best && i2 < bi)) { best = s2; bi = i2; }
        }
        if (lane == 0) {
            unsigned int su = __float_as_uint(best);
            su = (su & 0x80000000u) ? ~su : (su | 0x80000000u);   // sortable f32
            const u64 key = ((u64)su << 32) | (unsigned int)bi;
            atomicMin(&rowbest[r], key);
        }
    }
}

// Epilogue: winner -> coalesced gather + out_idx + loss partials.
__global__ __launch_bounds__(512)
void vq_epilogue_kernel(const u64* __restrict__ rowbest,
                        const float* __restrict__ x, const float* __restrict__ cb,
                        float* __restrict__ out_q, float* __restrict__ out_idx,
                        float* __restrict__ block_loss) {
    const int lane = threadIdx.x & 63;
    const int wv   = threadIdx.x >> 6;
    const int r    = blockIdx.x * 8 + wv;
    const int bi   = (int)(rowbest[r] & 0xFFFFFFFFull);
    const float ed = cb[(size_t)bi * DIM + lane];
    const float xd = x[(size_t)r * DIM + lane];
    out_q[(size_t)r * DIM + lane] = ed;
    if (lane == 0) out_idx[r] = (float)bi;
    float dd = ed - xd;
    dd = dd * dd;
#pragma unroll
    for (int off = 1; off < 64; off <<= 1) dd += __shfl_xor(dd, off);
    __shared__ float wsum[8];
    if (lane == 0) wsum[wv] = dd;
    __syncthreads();
    if (threadIdx.x == 0) {
        float s = 0.f;
#pragma unroll
        for (int w = 0; w < 8; ++w) s += wsum[w];
        block_loss[blockIdx.x] = s;
    }
}

__global__ __launch_bounds__(256)
void vq_loss_kernel(const float* __restrict__ block_loss,
                    float* __restrict__ out_loss) {
    float s = 0.f;
    for (int i = threadIdx.x; i < NROWS / 8; i += 256) s += block_loss[i];
#pragma unroll
    for (int off = 1; off < 64; off <<= 1) s += __shfl_xor(s, off);
    __shared__ float wsum[4];
    const int lane = threadIdx.x & 63, wv = threadIdx.x >> 6;
    if (lane == 0) wsum[wv] = s;
    __syncthreads();
    if (threadIdx.x == 0)
        *out_loss = ((wsum[0] + wsum[1]) + (wsum[2] + wsum[3])) * (1.25f / (float)NELEM);
}

extern "C" void kernel_launch(void* const* d_in, const int* in_sizes, int n_in,
                              void* d_out, int out_size, void* d_ws, size_t ws_size,
                              hipStream_t stream) {
    const float* x  = (const float*)d_in[0];
    const float* cb = (const float*)d_in[1];

    float* out_q    = (float*)d_out;
    float* out_loss = (float*)d_out + NELEM;
    float* out_idx  = (float*)d_out + NELEM + 1;

    float* wsf   = (float*)d_ws;
    float* norms = wsf;                                       // 8192 f32
    float* block_loss = norms + NUM_E;                        // 4096 f32
    u64*   rowbest = (u64*)(block_loss + NROWS / 8);          // 32768 u64 (8B-aligned)
    unsigned short* ebuf = (unsigned short*)(rowbest + NROWS);  // 8192*80 bf16

    hipMemsetAsync(rowbest, 0xFF, NROWS * sizeof(u64), stream);   // +inf keys
    vq_prep_cb<<<NUM_E / 256, 256, 0, stream>>>(cb, norms, ebuf);
    vq_fused_kernel<<<NROWS / ROWS_PB * 2, 512, 0, stream>>>(ebuf, x, cb, norms, rowbest);
    vq_epilogue_kernel<<<NROWS / 8, 512, 0, stream>>>(rowbest, x, cb,
                                                      out_q, out_idx, block_loss);
    vq_loss_kernel<<<1, 256, 0, stream>>>(block_loss, out_loss);
}

// Round 11
// 360.760 us; speedup vs baseline: 1.9327x; 1.9327x over previous
//
#include <hip/hip_runtime.h>

// VectorQuantizer on MI355X — round 11: register-lean waves + 3 blocks/CU.
// x: [32768, 64] f32, codebook: [8192, 64] f32.
// out (f32): [0..2097152) quantized, [2097152] loss, [2097153..) indices as floats.
//
// Grid = 512 rowgroups x 2 cand-halves = 1024 blocks; block = 512 thr (8 waves)
// x 64 rows x 4096 cands. Wave = (cand-split cs 0..3) x (row-half rh 0..1):
// holds bfrag for 32 rows ONLY (20 VGPRs) and scans 1024 cands (32 tiles),
// no A-prefetch depth (TLP hides latency at 24 waves/CU).
// Pass 1: per-(row, tile-pair) max of t_k = x.e_k - ||e_k||^2/2 into LDS.
// Hot pairs via __any on LDS maxes (registers; no conflict scan).
// Pass 2: re-MFMA hot pairs only, gather exact cand indices into LDS shortlist.
// Finalize: wave-per-8-rows EXACT rescore (round-2-validated numpy numerics,
// first-min tie rule) + u64 atomicMin (sortable score | idx) merge.
// Epilogue: coalesced gather + out_idx + loss. Overflow -> wave-parallel scan.

#define NUM_E   8192
#define DIM     64
#define KPAD    80
#define NROWS   32768
#define NELEM   2097152
#define CAP     32
#define TMARGIN 1.5e-4f
#define ROWS_PB 64
#define NT      32          // tiles of 32 cands per wave
#define FLTMAX  3.402823466e+38f

using bf16x8 = __attribute__((ext_vector_type(8))) short;
using f32x16 = __attribute__((ext_vector_type(16))) float;
typedef unsigned long long u64;

__device__ __forceinline__ unsigned int f2bf(float f) {
    unsigned int u = __float_as_uint(f);
    return (u + 0x7FFFu + ((u >> 16) & 1u)) >> 16;   // RNE to bf16
}

// numpy pairwise_sum(n=64) of elementwise squares (validated bit-exact r2+).
__device__ __forceinline__ float np_sumsq64_f4(const float4 v[16]) {
    float r0 = __fmul_rn(v[0].x, v[0].x), r1 = __fmul_rn(v[0].y, v[0].y);
    float r2 = __fmul_rn(v[0].z, v[0].z), r3 = __fmul_rn(v[0].w, v[0].w);
    float r4 = __fmul_rn(v[1].x, v[1].x), r5 = __fmul_rn(v[1].y, v[1].y);
    float r6 = __fmul_rn(v[1].z, v[1].z), r7 = __fmul_rn(v[1].w, v[1].w);
#pragma unroll
    for (int t = 1; t < 8; ++t) {
        r0 = __fadd_rn(r0, __fmul_rn(v[2 * t].x, v[2 * t].x));
        r1 = __fadd_rn(r1, __fmul_rn(v[2 * t].y, v[2 * t].y));
        r2 = __fadd_rn(r2, __fmul_rn(v[2 * t].z, v[2 * t].z));
        r3 = __fadd_rn(r3, __fmul_rn(v[2 * t].w, v[2 * t].w));
        r4 = __fadd_rn(r4, __fmul_rn(v[2 * t + 1].x, v[2 * t + 1].x));
        r5 = __fadd_rn(r5, __fmul_rn(v[2 * t + 1].y, v[2 * t + 1].y));
        r6 = __fadd_rn(r6, __fmul_rn(v[2 * t + 1].z, v[2 * t + 1].z));
        r7 = __fadd_rn(r7, __fmul_rn(v[2 * t + 1].w, v[2 * t + 1].w));
    }
    return __fadd_rn(__fadd_rn(__fadd_rn(r0, r1), __fadd_rn(r2, r3)),
                     __fadd_rn(__fadd_rn(r4, r5), __fadd_rn(r6, r7)));
}

__global__ __launch_bounds__(256)
void vq_prep_cb(const float* __restrict__ cb, float* __restrict__ norms,
                unsigned short* __restrict__ ebuf) {
    const int row = blockIdx.x * 256 + threadIdx.x;
    float4 e[16];
    const float4* p = reinterpret_cast<const float4*>(cb + row * DIM);
#pragma unroll
    for (int c = 0; c < 16; ++c) e[c] = p[c];
    const float nrm = np_sumsq64_f4(e);
    norms[row] = nrm;
    uint2* dst = reinterpret_cast<uint2*>(ebuf + (size_t)row * KPAD);
#pragma unroll
    for (int c = 0; c < 16; ++c) {
        uint2 w;
        w.x = f2bf(e[c].x) | (f2bf(e[c].y) << 16);
        w.y = f2bf(e[c].z) | (f2bf(e[c].w) << 16);
        dst[c] = w;
    }
    unsigned int* tail = reinterpret_cast<unsigned int*>(ebuf + (size_t)row * KPAD + DIM);
    tail[0] = f2bf(-0.5f * nrm);
#pragma unroll
    for (int j = 1; j < 8; ++j) tail[j] = 0u;
}

__global__ __launch_bounds__(512, 6)
void vq_fused_kernel(const unsigned short* __restrict__ ebuf,
                     const float* __restrict__ x, const float* __restrict__ cb,
                     const float* __restrict__ norms,
                     u64* __restrict__ rowbest) {
    const int tid  = threadIdx.x;
    const int lane = tid & 63;
    const int wid  = tid >> 6;
    const int cs   = wid >> 1;          // candidate split 0..3
    const int rh   = wid & 1;           // row half 0..1
    const int half = lane >> 5;         // k-half of fragment
    const int l31  = lane & 31;
    const int rowbase  = (blockIdx.x >> 1) * ROWS_PB;
    const int candbase = (blockIdx.x & 1) * 4096 + cs * 1024;
    const int myrow = rh * 32 + l31;    // row index within block (0..63)

    __shared__ float stmax[4][NT / 2][ROWS_PB];   // 16 KB
    __shared__ float sm[4][ROWS_PB];              // 1 KB
    __shared__ float sthr[ROWS_PB];
    __shared__ int   scnt[ROWS_PB];
    __shared__ int   sslots[ROWS_PB][CAP];        // 8 KB

    if (tid < ROWS_PB) scnt[tid] = 0;

    // ---- B fragments: this wave's 32 rows only (bit-identical f2bf packing) ----
    bf16x8 bfrag[5];
    {
        const float* xrow = x + (size_t)(rowbase + myrow) * DIM;
#pragma unroll
        for (int ks = 0; ks < 4; ++ks) {
            const float4* p = reinterpret_cast<const float4*>(xrow + ks * 16 + half * 8);
            float4 v0 = p[0], v1 = p[1];
            bf16x8 f;
            f[0] = (short)f2bf(v0.x); f[1] = (short)f2bf(v0.y);
            f[2] = (short)f2bf(v0.z); f[3] = (short)f2bf(v0.w);
            f[4] = (short)f2bf(v1.x); f[5] = (short)f2bf(v1.y);
            f[6] = (short)f2bf(v1.z); f[7] = (short)f2bf(v1.w);
            bfrag[ks] = f;
        }
        bf16x8 ft;   // K = [64,80): padded x tail = [1.0, 0 x15]
#pragma unroll
        for (int j = 0; j < 8; ++j) ft[j] = 0;
        if (half == 0) ft[0] = (short)0x3F80;   // bf16(1.0)
        bfrag[4] = ft;
    }

    const unsigned short* abase = ebuf + (size_t)(candbase + l31) * KPAD + half * 8;

    // ---- pass 1: per-(row, tile-pair) max into LDS ----
    float mpair = -FLTMAX;
    for (int t = 0; t < NT; ++t) {
        const unsigned short* ap = abase + (size_t)t * 32 * KPAD;
        bf16x8 a[5];
#pragma unroll
        for (int ks = 0; ks < 5; ++ks)
            a[ks] = *reinterpret_cast<const bf16x8*>(ap + ks * 16);
        f32x16 acc;
#pragma unroll
        for (int i = 0; i < 16; ++i) acc[i] = 0.f;
#pragma unroll
        for (int ks = 0; ks < 5; ++ks)
            acc = __builtin_amdgcn_mfma_f32_32x32x16_bf16(a[ks], bfrag[ks], acc, 0, 0, 0);
        float m0 = fmaxf(fmaxf(acc[0], acc[1]),  fmaxf(acc[2], acc[3]));
        float m1 = fmaxf(fmaxf(acc[4], acc[5]),  fmaxf(acc[6], acc[7]));
        float m2 = fmaxf(fmaxf(acc[8], acc[9]),  fmaxf(acc[10], acc[11]));
        float m3 = fmaxf(fmaxf(acc[12], acc[13]), fmaxf(acc[14], acc[15]));
        mpair = fmaxf(mpair, fmaxf(fmaxf(m0, m1), fmaxf(m2, m3)));
        if (t & 1) {
            const float p = fmaxf(mpair, __shfl_xor(mpair, 32));   // merge k-halves
            if (half == 0) stmax[cs][t >> 1][myrow] = p;
            mpair = -FLTMAX;
        }
    }
    __syncthreads();

    // ---- fold -> per-row threshold ----
    if (tid < 256) {
        const int w = tid >> 6, r = tid & 63;
        float m = stmax[w][0][r];
#pragma unroll
        for (int tp = 1; tp < NT / 2; ++tp) m = fmaxf(m, stmax[w][tp][r]);
        sm[w][r] = m;
    }
    __syncthreads();
    if (tid < ROWS_PB) {
        const float m01 = fmaxf(sm[0][tid], sm[1][tid]);
        const float m23 = fmaxf(sm[2][tid], sm[3][tid]);
        sthr[tid] = fmaxf(m01, m23) - TMARGIN;
    }
    __syncthreads();

    const float myth = sthr[myrow];

    // ---- hot-pair mask (this wave's rows only) ----
    unsigned int hot = 0;
#pragma unroll
    for (int tp = 0; tp < NT / 2; ++tp)
        if (__any(stmax[cs][tp][myrow] >= myth)) hot |= 1u << tp;

    // ---- pass 2: re-MFMA hot pairs, per-candidate gather ----
    while (hot) {
        const int tp = __ffs(hot) - 1;
        hot &= hot - 1;
#pragma unroll
        for (int tt = 0; tt < 2; ++tt) {
            const int t = 2 * tp + tt;
            const unsigned short* ap = abase + (size_t)t * 32 * KPAD;
            bf16x8 a[5];
#pragma unroll
            for (int ks = 0; ks < 5; ++ks)
                a[ks] = *reinterpret_cast<const bf16x8*>(ap + ks * 16);
            f32x16 acc;
#pragma unroll
            for (int i = 0; i < 16; ++i) acc[i] = 0.f;
#pragma unroll
            for (int ks = 0; ks < 5; ++ks)
                acc = __builtin_amdgcn_mfma_f32_32x32x16_bf16(a[ks], bfrag[ks], acc, 0, 0, 0);
            float m0 = fmaxf(fmaxf(acc[0], acc[1]),  fmaxf(acc[2], acc[3]));
            float m1 = fmaxf(fmaxf(acc[4], acc[5]),  fmaxf(acc[6], acc[7]));
            float m2 = fmaxf(fmaxf(acc[8], acc[9]),  fmaxf(acc[10], acc[11]));
            float m3 = fmaxf(fmaxf(acc[12], acc[13]), fmaxf(acc[14], acc[15]));
            const float tm = fmaxf(fmaxf(m0, m1), fmaxf(m2, m3));
            if (__any(tm >= myth)) {
#pragma unroll
                for (int r = 0; r < 16; ++r) {
                    if (acc[r] >= myth) {
                        const int crow = (r & 3) + 8 * (r >> 2) + 4 * half;
                        const int pos = atomicAdd(&scnt[myrow], 1);
                        if (pos < CAP)
                            sslots[myrow][pos] = candbase + t * 32 + crow;
                    }
                }
            }
        }
    }
    __syncthreads();

    // ---- finalize: wave per 8 rows; exact rescore + u64 atomicMin merge ----
    for (int i = 0; i < 8; ++i) {
        const int lr = wid * 8 + i;
        const int r  = rowbase + lr;
        const int c0 = scnt[lr];
        const bool okc = (c0 <= CAP);
        const int ncand = okc ? c0 : 4096;   // overflow -> scan this block's half
        float4 xr[16];
        const float4* xp = reinterpret_cast<const float4*>(x + (size_t)r * DIM);
#pragma unroll
        for (int c = 0; c < 16; ++c) xr[c] = xp[c];
        const float sx = np_sumsq64_f4(xr);   // identical fn -> bit-identical
        float best = FLTMAX;
        int bi = 0x7FFFFFFF;
        for (int j = lane; j < ncand; j += 64) {
            const int k = okc ? sslots[lr][j] : ((blockIdx.x & 1) * 4096 + j);
            const float4* ep4 = reinterpret_cast<const float4*>(cb + (size_t)k * DIM);
            float dot = 0.f;   // sequential fmaf chain d=0..63 (exact replication)
#pragma unroll
            for (int c = 0; c < 16; c += 4) {
                float4 e0 = ep4[c], e1 = ep4[c + 1], e2 = ep4[c + 2], e3 = ep4[c + 3];
                dot = fmaf(xr[c].x,     e0.x, dot); dot = fmaf(xr[c].y,     e0.y, dot);
                dot = fmaf(xr[c].z,     e0.z, dot); dot = fmaf(xr[c].w,     e0.w, dot);
                dot = fmaf(xr[c + 1].x, e1.x, dot); dot = fmaf(xr[c + 1].y, e1.y, dot);
                dot = fmaf(xr[c + 1].z, e1.z, dot); dot = fmaf(xr[c + 1].w, e1.w, dot);
                dot = fmaf(xr[c + 2].x, e2.x, dot); dot = fmaf(xr[c + 2].y, e2.y, dot);
                dot = fmaf(xr[c + 2].z, e2.z, dot); dot = fmaf(xr[c + 2].w, e2.w, dot);
                dot = fmaf(xr[c + 3].x, e3.x, dot); dot = fmaf(xr[c + 3].y, e3.y, dot);
                dot = fmaf(xr[c + 3].z, e3.z, dot); dot = fmaf(xr[c + 3].w, e3.w, dot);
            }
            const float t1 = __fadd_rn(sx, norms[k]);
            const float d2 = __fadd_rn(dot, dot);
            const float sc = __fsub_rn(t1, d2);
            if (sc < best || (sc == best && k < bi)) { best = sc; bi = k; }
        }
#pragma unroll
        for (int off = 1; off < 64; off <<= 1) {   // lexicographic first-min
            const float s2 = __shfl_xor(best, off);
            const int   i2 = __shfl_xor(bi, off);
            if (s2 < best || (s2 == best && i2 < bi)) { best = s2; bi = i2; }
        }
        if (lane == 0) {
            unsigned int su = __float_as_uint(best);
            su = (su & 0x80000000u) ? ~su : (su | 0x80000000u);   // sortable f32
            const u64 key = ((u64)su << 32) | (unsigned int)bi;
            atomicMin(&rowbest[r], key);
        }
    }
}

// Epilogue: winner -> coalesced gather + out_idx + loss partials.
__global__ __launch_bounds__(512)
void vq_epilogue_kernel(const u64* __restrict__ rowbest,
                        const float* __restrict__ x, const float* __restrict__ cb,
                        float* __restrict__ out_q, float* __restrict__ out_idx,
                        float* __restrict__ block_loss) {
    const int lane = threadIdx.x & 63;
    const int wv   = threadIdx.x >> 6;
    const int r    = blockIdx.x * 8 + wv;
    const int bi   = (int)(rowbest[r] & 0xFFFFFFFFull);
    const float ed = cb[(size_t)bi * DIM + lane];
    const float xd = x[(size_t)r * DIM + lane];
    out_q[(size_t)r * DIM + lane] = ed;
    if (lane == 0) out_idx[r] = (float)bi;
    float dd = ed - xd;
    dd = dd * dd;
#pragma unroll
    for (int off = 1; off < 64; off <<= 1) dd += __shfl_xor(dd, off);
    __shared__ float wsum[8];
    if (lane == 0) wsum[wv] = dd;
    __syncthreads();
    if (threadIdx.x == 0) {
        float s = 0.f;
#pragma unroll
        for (int w = 0; w < 8; ++w) s += wsum[w];
        block_loss[blockIdx.x] = s;
    }
}

__global__ __launch_bounds__(256)
void vq_loss_kernel(const float* __restrict__ block_loss,
                    float* __restrict__ out_loss) {
    float s = 0.f;
    for (int i = threadIdx.x; i < NROWS / 8; i += 256) s += block_loss[i];
#pragma unroll
    for (int off = 1; off < 64; off <<= 1) s += __shfl_xor(s, off);
    __shared__ float wsum[4];
    const int lane = threadIdx.x & 63, wv = threadIdx.x >> 6;
    if (lane == 0) wsum[wv] = s;
    __syncthreads();
    if (threadIdx.x == 0)
        *out_loss = ((wsum[0] + wsum[1]) + (wsum[2] + wsum[3])) * (1.25f / (float)NELEM);
}

extern "C" void kernel_launch(void* const* d_in, const int* in_sizes, int n_in,
                              void* d_out, int out_size, void* d_ws, size_t ws_size,
                              hipStream_t stream) {
    const float* x  = (const float*)d_in[0];
    const float* cb = (const float*)d_in[1];

    float* out_q    = (float*)d_out;
    float* out_loss = (float*)d_out + NELEM;
    float* out_idx  = (float*)d_out + NELEM + 1;

    float* wsf   = (float*)d_ws;
    float* norms = wsf;                                       // 8192 f32
    float* block_loss = norms + NUM_E;                        // 4096 f32
    u64*   rowbest = (u64*)(block_loss + NROWS / 8);          // 32768 u64 (8B-aligned)
    unsigned short* ebuf = (unsigned short*)(rowbest + NROWS);  // 8192*80 bf16

    hipMemsetAsync(rowbest, 0xFF, NROWS * sizeof(u64), stream);   // +inf keys
    vq_prep_cb<<<NUM_E / 256, 256, 0, stream>>>(cb, norms, ebuf);
    vq_fused_kernel<<<NROWS / ROWS_PB * 2, 512, 0, stream>>>(ebuf, x, cb, norms, rowbest);
    vq_epilogue_kernel<<<NROWS / 8, 512, 0, stream>>>(rowbest, x, cb,
                                                      out_q, out_idx, block_loss);
    vq_loss_kernel<<<1, 256, 0, stream>>>(block_loss, out_loss);
}